// Round 1
// baseline (161.747 us; speedup 1.0000x reference)
//
#include <hip/hip_runtime.h>

// CompiledLogicNet: boolean circuit, batch bit-packed into 64-bit words.
// BATCH=4096 -> 64 words of 64 bits. State per layer: [WIDTH][64] u64 = 8.2MB.

#define BATCH 4096
#define NIN   784
#define WIDTH 16000
#define NH    4
#define NC    10
#define NW    (BATCH / 64)   // 64 words along batch

typedef unsigned long long u64;

// Pack x [BATCH, NIN] int32 (0/1) -> xw [NIN][NW] u64.
// One wave per (input i, word w); lane b supplies batch row w*64+b.
__global__ void pack_kernel(const int* __restrict__ x, u64* __restrict__ xw) {
    int gid  = blockIdx.x * blockDim.x + threadIdx.x;
    int wave = gid >> 6;
    int lane = threadIdx.x & 63;
    if (wave >= NIN * NW) return;
    int i = wave / NW;
    int w = wave % NW;
    int v = x[(size_t)(w * 64 + lane) * NIN + i];
    u64 m = __ballot(v != 0);
    if (lane == 0) xw[(size_t)i * NW + w] = m;
}

// One logic layer: gate g, word w.
// hout[g][w] = (hin[ia[g]][w] ^ ma) & (hin[ib[g]][w] ^ mb)
__global__ void layer_kernel(const u64* __restrict__ hin,
                             const int* __restrict__ ia,
                             const int* __restrict__ ib,
                             const int* __restrict__ nf,   // [WIDTH][2]
                             u64* __restrict__ hout) {
    int gid = blockIdx.x * blockDim.x + threadIdx.x;
    int g = gid >> 6;
    int w = threadIdx.x & 63;
    if (g >= WIDTH) return;
    int a = ia[g];
    int b = ib[g];
    u64 ma = nf[2 * g]     ? ~0ull : 0ull;
    u64 mb = nf[2 * g + 1] ? ~0ull : 0ull;
    u64 av = hin[(size_t)a * NW + w];
    u64 bv = hin[(size_t)b * NW + w];
    hout[(size_t)g * NW + w] = (av ^ ma) & (bv ^ mb);
}

// GroupSum: out[b][c] = popcount over the 1600 gates of class c, bit b.
// One wave per (word w, class c); lane = bit position within word.
__global__ void gsum_kernel(const u64* __restrict__ h, int* __restrict__ out) {
    int gid  = blockIdx.x * blockDim.x + threadIdx.x;
    int wave = gid >> 6;
    int lane = threadIdx.x & 63;
    if (wave >= NW * NC) return;
    int w = wave / NC;
    int c = wave % NC;
    const int G = WIDTH / NC;  // 1600
    const u64* p = h + (size_t)(c * G) * NW + w;
    int cnt = 0;
    for (int j = 0; j < G; ++j) {
        u64 v = p[(size_t)j * NW];
        cnt += (int)((v >> lane) & 1ull);
    }
    int b = w * 64 + lane;
    out[(size_t)b * NC + c] = cnt;
}

extern "C" void kernel_launch(void* const* d_in, const int* in_sizes, int n_in,
                              void* d_out, int out_size, void* d_ws, size_t ws_size,
                              hipStream_t stream) {
    const int* x      = (const int*)d_in[0];  // [4096,784] 0/1
    const int* idx_a0 = (const int*)d_in[1];  // [16000]
    const int* idx_b0 = (const int*)d_in[2];  // [16000]
    const int* neg0   = (const int*)d_in[3];  // [16000,2]
    const int* idx_a  = (const int*)d_in[4];  // [4,16000]
    const int* idx_b  = (const int*)d_in[5];  // [4,16000]
    const int* neg    = (const int*)d_in[6];  // [4,16000,2]
    int* out = (int*)d_out;                   // [4096,10]

    char* ws = (char*)d_ws;
    u64* xw = (u64*)ws;                                   // 784*64*8   = 401,408 B
    u64* hA = (u64*)(ws + 512 * 1024);                    // 16000*64*8 = 8,192,000 B
    u64* hB = (u64*)(ws + 512 * 1024 + 8 * 1024 * 1024 + 512 * 1024);

    // 1. pack input bits
    {
        int threads = NIN * NW * 64;
        pack_kernel<<<(threads + 255) / 256, 256, 0, stream>>>(x, xw);
    }
    // 2. input layer: xw -> hA
    {
        int threads = WIDTH * 64;
        layer_kernel<<<(threads + 255) / 256, 256, 0, stream>>>(xw, idx_a0, idx_b0, neg0, hA);
    }
    // 3. hidden layers, ping-pong hA <-> hB
    u64* cur = hA;
    u64* nxt = hB;
    for (int l = 0; l < NH; ++l) {
        int threads = WIDTH * 64;
        layer_kernel<<<(threads + 255) / 256, 256, 0, stream>>>(
            cur, idx_a + (size_t)l * WIDTH, idx_b + (size_t)l * WIDTH,
            neg + (size_t)l * WIDTH * 2, nxt);
        u64* t = cur; cur = nxt; nxt = t;
    }
    // 4. group popcount -> logits
    {
        int threads = NW * NC * 64;
        gsum_kernel<<<(threads + 255) / 256, 256, 0, stream>>>(cur, out);
    }
}

// Round 2
// 118.237 us; speedup vs baseline: 1.3680x; 1.3680x over previous
//
#include <hip/hip_runtime.h>

// CompiledLogicNet: boolean circuit, batch bit-packed into 64-bit words.
// BATCH=4096 -> 64 words of 64 bits. State per layer: [WIDTH][64] u64 = 8.2MB.

#define BATCH 4096
#define NIN   784
#define WIDTH 16000
#define NH    4
#define NC    10
#define NW    (BATCH / 64)   // 64 words along batch
#define GPC   (WIDTH / NC)   // 1600 gates per class
#define NCHUNK 25            // gsum chunks per class (64 gates each)

typedef unsigned long long u64;
typedef unsigned char u8;

// ---------------------------------------------------------------------------
// Pack x [BATCH, NIN] int32 (0/1) -> xw [NIN][NW] u64, via LDS transpose so
// global reads are coalesced (lane = consecutive i).
// Grid: NW * 13 blocks (13 i-chunks of 64 cover 784), 256 threads.
__global__ void pack_kernel(const int* __restrict__ x, u64* __restrict__ xw) {
    int w  = blockIdx.x / 13;
    int ic = blockIdx.x % 13;
    int i0 = ic * 64;
    int lane = threadIdx.x & 63;
    int wid  = threadIdx.x >> 6;

    __shared__ int tile[64][65];  // +1 pad: bank (lane+col)%32, 2-way = free

    int i = i0 + lane;
#pragma unroll
    for (int k = 0; k < 16; ++k) {
        int r = k * 4 + wid;  // batch row within word
        tile[r][lane] = (i < NIN) ? x[(size_t)(w * 64 + r) * NIN + i] : 0;
    }
    __syncthreads();
#pragma unroll
    for (int k = 0; k < 16; ++k) {
        int col = wid * 16 + k;
        int v = tile[lane][col];
        u64 m = __ballot(v != 0);
        if (lane == 0 && (i0 + col) < NIN)
            xw[(size_t)(i0 + col) * NW + w] = m;
    }
}

// ---------------------------------------------------------------------------
// One logic layer, vectorized: 32 lanes per gate, each handling a word pair.
// hout[g][*] = (hin[ia[g]][*] ^ ma) & (hin[ib[g]][*] ^ mb)
__global__ void layer_kernel(const u64* __restrict__ hin,
                             const int* __restrict__ ia,
                             const int* __restrict__ ib,
                             const int* __restrict__ nf,   // [WIDTH][2]
                             u64* __restrict__ hout) {
    int gid = blockIdx.x * blockDim.x + threadIdx.x;
    int g  = gid >> 5;        // gate
    int wp = gid & 31;        // word-pair index
    if (g >= WIDTH) return;
    int a = ia[g];
    int b = ib[g];
    u64 ma = nf[2 * g]     ? ~0ull : 0ull;
    u64 mb = nf[2 * g + 1] ? ~0ull : 0ull;
    const ulonglong2* pa = (const ulonglong2*)(hin + (size_t)a * NW);
    const ulonglong2* pb = (const ulonglong2*)(hin + (size_t)b * NW);
    ulonglong2 va = pa[wp];
    ulonglong2 vb = pb[wp];
    ulonglong2 r;
    r.x = (va.x ^ ma) & (vb.x ^ mb);
    r.y = (va.y ^ ma) & (vb.y ^ mb);
    ((ulonglong2*)(hout + (size_t)g * NW))[wp] = r;
}

// ---------------------------------------------------------------------------
// GroupSum phase 1: bit-sliced vertical popcount.
// Grid: NC * NCHUNK blocks (250), 256 threads. Block = (class c, 64-gate chunk).
// Wave wid handles 16 gates; lane = batch word w (coalesced 512B row reads).
// Per-thread CSA into 5 planes (count<=16), LDS ripple-merge of 4 waves into
// 7 planes (count<=64), then all 256 threads extract 16 bits each -> u8
// partial[chunk][c][w*64+b].
__global__ void gsum1_kernel(const u64* __restrict__ h, u8* __restrict__ partial) {
    int c     = blockIdx.x / NCHUNK;
    int chunk = blockIdx.x % NCHUNK;
    int wid  = threadIdx.x >> 6;
    int lane = threadIdx.x & 63;

    int g0 = c * GPC + chunk * 64 + wid * 16;
    const u64* p = h + (size_t)g0 * NW + lane;

    u64 pl[5] = {0, 0, 0, 0, 0};
#pragma unroll
    for (int j = 0; j < 16; ++j) {
        u64 carry = p[(size_t)j * NW];
#pragma unroll
        for (int q = 0; q < 5; ++q) {
            u64 t = pl[q];
            pl[q] = t ^ carry;
            carry = t & carry;
        }
    }

    __shared__ u64 lds[4][64][5];
#pragma unroll
    for (int q = 0; q < 5; ++q) lds[wid][lane][q] = pl[q];
    __syncthreads();

    // Every thread re-merges the 4 waves' planes for w = lane (redundant but
    // parallel), producing a 7-plane count (<=64) per bit.
    u64 acc[7];
#pragma unroll
    for (int q = 0; q < 5; ++q) acc[q] = lds[0][lane][q];
    acc[5] = 0; acc[6] = 0;
#pragma unroll
    for (int s = 1; s < 4; ++s) {
        u64 carry = 0;
#pragma unroll
        for (int q = 0; q < 5; ++q) {
            u64 a = acc[q], b = lds[s][lane][q];
            u64 x = a ^ b;
            acc[q] = x ^ carry;
            carry = (a & b) | (carry & x);
        }
#pragma unroll
        for (int q = 5; q < 7; ++q) {
            u64 a = acc[q];
            acc[q] = a ^ carry;
            carry = a & carry;
        }
    }

    // Extract bits b = wid*16 .. wid*16+15 for w = lane; pack 8 counts per u64.
    size_t base = ((size_t)chunk * NC + c) * 4096 + (size_t)lane * 64 + wid * 16;
    u64* pout = (u64*)(partial + base);
#pragma unroll
    for (int half = 0; half < 2; ++half) {
        u64 packed = 0;
#pragma unroll
        for (int j = 0; j < 8; ++j) {
            int b = wid * 16 + half * 8 + j;
            u64 cnt = 0;
#pragma unroll
            for (int q = 0; q < 7; ++q) cnt |= ((acc[q] >> b) & 1ull) << q;
            packed |= cnt << (8 * j);
        }
        pout[half] = packed;
    }
}

// GroupSum phase 2: out[b][c] = sum over 25 chunks of partial[chunk][c][b].
// t enumerated c-major so the partial reads are coalesced in b.
__global__ void gsum2_kernel(const u8* __restrict__ partial, int* __restrict__ out) {
    int t = blockIdx.x * blockDim.x + threadIdx.x;
    if (t >= NC * 4096) return;
    int c = t >> 12;      // t / 4096
    int b = t & 4095;
    int s = 0;
#pragma unroll
    for (int chunk = 0; chunk < NCHUNK; ++chunk)
        s += partial[((size_t)chunk * NC + c) * 4096 + b];
    out[(size_t)b * NC + c] = s;
}

// ---------------------------------------------------------------------------
extern "C" void kernel_launch(void* const* d_in, const int* in_sizes, int n_in,
                              void* d_out, int out_size, void* d_ws, size_t ws_size,
                              hipStream_t stream) {
    const int* x      = (const int*)d_in[0];  // [4096,784] 0/1
    const int* idx_a0 = (const int*)d_in[1];  // [16000]
    const int* idx_b0 = (const int*)d_in[2];  // [16000]
    const int* neg0   = (const int*)d_in[3];  // [16000,2]
    const int* idx_a  = (const int*)d_in[4];  // [4,16000]
    const int* idx_b  = (const int*)d_in[5];  // [4,16000]
    const int* neg    = (const int*)d_in[6];  // [4,16000,2]
    int* out = (int*)d_out;                   // [4096,10]

    char* ws = (char*)d_ws;
    u64* xw = (u64*)ws;                            // 784*64*8   = 401,408 B
    u64* hA = (u64*)(ws + 401408);                 // 16000*64*8 = 8,192,000 B
    u64* hB = (u64*)(ws + 401408 + 8192000);       // 8,192,000 B
    u8* partial = (u8*)(ws + 401408 + 2 * 8192000);// 25*10*4096 = 1,024,000 B

    // 1. pack input bits (transposing, coalesced)
    pack_kernel<<<NW * 13, 256, 0, stream>>>(x, xw);

    // 2. input layer: xw -> hA
    {
        int threads = WIDTH * 32;
        layer_kernel<<<threads / 256, 256, 0, stream>>>(xw, idx_a0, idx_b0, neg0, hA);
    }
    // 3. hidden layers, ping-pong hA <-> hB
    u64* cur = hA;
    u64* nxt = hB;
    for (int l = 0; l < NH; ++l) {
        int threads = WIDTH * 32;
        layer_kernel<<<threads / 256, 256, 0, stream>>>(
            cur, idx_a + (size_t)l * WIDTH, idx_b + (size_t)l * WIDTH,
            neg + (size_t)l * WIDTH * 2, nxt);
        u64* t = cur; cur = nxt; nxt = t;
    }
    // 4. group popcount -> logits (two phases)
    gsum1_kernel<<<NC * NCHUNK, 256, 0, stream>>>(cur, partial);
    gsum2_kernel<<<(NC * 4096 + 255) / 256, 256, 0, stream>>>(partial, out);
}

// Round 3
// 92.195 us; speedup vs baseline: 1.7544x; 1.2825x over previous
//
#include <hip/hip_runtime.h>

// CompiledLogicNet fully fused: one block per u32 batch-column (32 samples).
// State [16000] u32 lives in LDS, double-buffered (2x64KB). Gathers = LDS reads.
// 128 blocks x 1024 threads, 1 block/CU (LDS-bound). GroupSum via CSA planes.

#define NIN   784
#define WIDTH 16000
#define NH    4
#define NC    10
#define GPC   1600     // gates per class
#define NBLK  128      // u32 columns: 4096 batch / 32
#define TPB   1024
#define SSTR  13       // gsum scratch stride: 12 planes + 1 pad (kills 8-way bank conflict)

typedef unsigned int u32;

// ---------------------------------------------------------------------------
// Pack (idx_a, idx_b, neg) -> desc[l][g] = ia | ib<<14 | na<<28 | nb<<29
__global__ void desc_kernel(const int* __restrict__ ia0, const int* __restrict__ ib0,
                            const int* __restrict__ n0,
                            const int* __restrict__ ia, const int* __restrict__ ib,
                            const int* __restrict__ n, u32* __restrict__ desc) {
    int t = blockIdx.x * blockDim.x + threadIdx.x;
    if (t >= (NH + 1) * WIDTH) return;
    int l = t / WIDTH, g = t % WIDTH;
    int a, b, na, nb;
    if (l == 0) { a = ia0[g]; b = ib0[g]; na = n0[2 * g]; nb = n0[2 * g + 1]; }
    else {
        int o = (l - 1) * WIDTH + g;
        a = ia[o]; b = ib[o]; na = n[2 * o]; nb = n[2 * o + 1];
    }
    desc[t] = (u32)a | ((u32)b << 14) | (na ? (1u << 28) : 0u) | (nb ? (1u << 29) : 0u);
}

// ---------------------------------------------------------------------------
__device__ __forceinline__ void gate(const u32* __restrict__ src, u32* __restrict__ dst,
                                     const u32* __restrict__ dp, int g) {
    u32 d  = dp[g];
    u32 a  = d & 0x3FFFu;
    u32 b  = (d >> 14) & 0x3FFFu;
    u32 ma = 0u - ((d >> 28) & 1u);
    u32 mb = 0u - ((d >> 29) & 1u);
    dst[g] = (src[a] ^ ma) & (src[b] ^ mb);
}

__launch_bounds__(TPB)
__global__ void net_kernel(const int* __restrict__ x, const u32* __restrict__ desc,
                           int* __restrict__ out) {
    __shared__ u32 xw[NIN];
    __shared__ u32 bufA[WIDTH];
    __shared__ u32 bufB[WIDTH];   // doubles as gsum scratch at the end

    int w = blockIdx.x;
    int t = threadIdx.x;

    // ---- pack: xw[i] bit r = x[w*32+r][i] (coalesced along i) ----
    if (t < NIN) {
        const int* base = x + (size_t)(w * 32) * NIN + t;
        u32 acc = 0;
#pragma unroll
        for (int r = 0; r < 32; ++r)
            acc |= (base[(size_t)r * NIN] != 0 ? 1u : 0u) << r;
        xw[t] = acc;
    }
    __syncthreads();

    // ---- input layer: xw -> bufA ----
    {
        const u32* dp = desc;
#pragma unroll 3
        for (int it = 0; it < 15; ++it) gate(xw, bufA, dp, t + it * TPB);
        if (t < WIDTH - 15 * TPB) gate(xw, bufA, dp, t + 15 * TPB);
    }

    // ---- hidden layers, ping-pong in LDS ----
    u32* cur = bufA;
    u32* nxt = bufB;
    for (int l = 1; l <= NH; ++l) {
        __syncthreads();
        const u32* dp = desc + (size_t)l * WIDTH;
#pragma unroll 3
        for (int it = 0; it < 15; ++it) gate(cur, nxt, dp, t + it * TPB);
        if (t < WIDTH - 15 * TPB) gate(cur, nxt, dp, t + 15 * TPB);
        u32* tmp = cur; cur = nxt; nxt = tmp;
    }
    __syncthreads();
    // after 4 swaps: cur == bufA (result), nxt == bufB (free -> scratch)

    // ---- GroupSum: CSA vertical popcount over each class's 1600 gates ----
    u32* scratch = nxt;
    // Phase A: 1000 threads: (class c, slot j) CSA 16 gates -> 5 planes (<=16)
    if (t < NC * 100) {
        int c = t / 100, j = t % 100;
        u32 p[12];
#pragma unroll
        for (int q = 0; q < 12; ++q) p[q] = 0;
#pragma unroll
        for (int k = 0; k < 16; ++k) {
            u32 carry = cur[c * GPC + k * 100 + j];
#pragma unroll
            for (int q = 0; q < 5; ++q) { u32 s = p[q]; p[q] = s ^ carry; carry = s & carry; }
        }
        u32* sp = scratch + (c * 100 + j) * SSTR;
#pragma unroll
        for (int q = 0; q < 12; ++q) sp[q] = p[q];
    }

    // Phase B: pairwise tree-merge (12-plane ripple adder), 100->50->25->13->7->4->2->1
    const int widths[8] = {100, 50, 25, 13, 7, 4, 2, 1};
    for (int s = 0; s < 7; ++s) {
        int W = widths[s], Wo = widths[s + 1];
        u32 p[12];
        bool act = (t < NC * Wo);
        int c = 0, j = 0;
        __syncthreads();
        if (act) {
            c = t / Wo; j = t % Wo;
            const u32* pa = scratch + (c * 100 + 2 * j) * SSTR;
#pragma unroll
            for (int q = 0; q < 12; ++q) p[q] = pa[q];
            if (2 * j + 1 < W) {
                const u32* pb = scratch + (c * 100 + 2 * j + 1) * SSTR;
                u32 carry = 0;
#pragma unroll
                for (int q = 0; q < 12; ++q) {
                    u32 a = p[q], b = pb[q];
                    u32 xr = a ^ b;
                    p[q] = xr ^ carry;
                    carry = (a & b) | (carry & xr);
                }
            }
        }
        __syncthreads();
        if (act) {
            u32* po = scratch + (c * 100 + j) * SSTR;
#pragma unroll
            for (int q = 0; q < 12; ++q) po[q] = p[q];
        }
    }
    __syncthreads();

    // Phase C: extract per-bit counts, write logits
    if (t < NC * 32) {
        int c = t / 32, bit = t % 32;
        const u32* sp = scratch + (c * 100) * SSTR;
        int cnt = 0;
#pragma unroll
        for (int q = 0; q < 12; ++q) cnt += (int)((sp[q] >> bit) & 1u) << q;
        out[((size_t)w * 32 + bit) * NC + c] = cnt;
    }
}

// ---------------------------------------------------------------------------
extern "C" void kernel_launch(void* const* d_in, const int* in_sizes, int n_in,
                              void* d_out, int out_size, void* d_ws, size_t ws_size,
                              hipStream_t stream) {
    const int* x      = (const int*)d_in[0];  // [4096,784] 0/1
    const int* idx_a0 = (const int*)d_in[1];  // [16000]
    const int* idx_b0 = (const int*)d_in[2];  // [16000]
    const int* neg0   = (const int*)d_in[3];  // [16000,2]
    const int* idx_a  = (const int*)d_in[4];  // [4,16000]
    const int* idx_b  = (const int*)d_in[5];  // [4,16000]
    const int* neg    = (const int*)d_in[6];  // [4,16000,2]
    int* out = (int*)d_out;                   // [4096,10]

    u32* desc = (u32*)d_ws;                   // (NH+1)*WIDTH*4 = 320,000 B

    int ndesc = (NH + 1) * WIDTH;
    desc_kernel<<<(ndesc + 255) / 256, 256, 0, stream>>>(
        idx_a0, idx_b0, neg0, idx_a, idx_b, neg, desc);

    net_kernel<<<NBLK, TPB, 0, stream>>>(x, desc, out);
}

// Round 4
// 88.660 us; speedup vs baseline: 1.8244x; 1.0399x over previous
//
#include <hip/hip_runtime.h>

// CompiledLogicNet fully fused: one block per u32 batch-column (32 samples).
// State [16384] u32 (16000 padded) in LDS, double-buffered. Gathers = LDS reads,
// software-pipelined 16-deep; desc loads prefetched across layers.

#define NIN   784
#define WIDTH 16000
#define SW    16384    // padded width (16 * TPB)
#define NH    4
#define NC    10
#define GPC   1600     // gates per class
#define NBLK  128      // u32 columns: 4096 batch / 32
#define TPB   1024
#define NIT   16       // gates per thread per layer (SW / TPB)
#define SSTR  13       // gsum scratch stride: 12 planes + 1 pad

typedef unsigned int u32;

// ---------------------------------------------------------------------------
// Pack (idx_a, idx_b, neg) -> desc[l][g] = ia | ib<<14 | na<<28 | nb<<29,
// padded to SW per layer (pad gates: a=b=0, no neg -> harmless).
__global__ void desc_kernel(const int* __restrict__ ia0, const int* __restrict__ ib0,
                            const int* __restrict__ n0,
                            const int* __restrict__ ia, const int* __restrict__ ib,
                            const int* __restrict__ n, u32* __restrict__ desc) {
    int t = blockIdx.x * blockDim.x + threadIdx.x;
    if (t >= (NH + 1) * SW) return;
    int l = t >> 14;          // t / SW
    int g = t & (SW - 1);     // t % SW
    u32 d = 0;
    if (g < WIDTH) {
        int a, b, na, nb;
        if (l == 0) { a = ia0[g]; b = ib0[g]; na = n0[2 * g]; nb = n0[2 * g + 1]; }
        else {
            int o = (l - 1) * WIDTH + g;
            a = ia[o]; b = ib[o]; na = n[2 * o]; nb = n[2 * o + 1];
        }
        d = (u32)a | ((u32)b << 14) | (na ? (1u << 28) : 0u) | (nb ? (1u << 29) : 0u);
    }
    desc[t] = d;
}

// ---------------------------------------------------------------------------
__launch_bounds__(TPB)
__global__ void net_kernel(const int* __restrict__ x, const u32* __restrict__ desc,
                           int* __restrict__ out) {
    __shared__ u32 xw[NIN];
    __shared__ u32 bufA[SW];
    __shared__ u32 bufB[SW];   // doubles as gsum scratch at the end

    int w = blockIdx.x;
    int t = threadIdx.x;

    // prefetch layer-0 descriptors while we pack
    u32 dreg[NIT];
#pragma unroll
    for (int it = 0; it < NIT; ++it) dreg[it] = desc[t + it * TPB];

    // ---- pack: xw[i] bit r = x[w*32+r][i] (coalesced along i) ----
    if (t < NIN) {
        const int* base = x + (size_t)(w * 32) * NIN + t;
        u32 acc = 0;
#pragma unroll
        for (int r = 0; r < 32; ++r)
            acc |= (base[(size_t)r * NIN] != 0 ? 1u : 0u) << r;
        xw[t] = acc;
    }
    __syncthreads();

    // ---- 5 layers, ping-pong LDS; reads batched 16-deep, descs prefetched ----
    u32* cur = xw;
#pragma unroll
    for (int l = 0; l <= NH; ++l) {
        u32* dst = (l & 1) ? bufB : bufA;   // A,B,A,B,A -> result in bufA
        u32 dn[NIT];
        if (l < NH) {
            const u32* dq = desc + (size_t)(l + 1) * SW;
#pragma unroll
            for (int it = 0; it < NIT; ++it) dn[it] = dq[t + it * TPB];
        }
#pragma unroll
        for (int half = 0; half < 2; ++half) {
            u32 av[8], bv[8];
#pragma unroll
            for (int j = 0; j < 8; ++j) {
                u32 d = dreg[half * 8 + j];
                av[j] = cur[d & 0x3FFFu];
                bv[j] = cur[(d >> 14) & 0x3FFFu];
            }
#pragma unroll
            for (int j = 0; j < 8; ++j) {
                int it = half * 8 + j;
                u32 d = dreg[it];
                u32 ma = 0u - ((d >> 28) & 1u);
                u32 mb = 0u - ((d >> 29) & 1u);
                dst[t + it * TPB] = (av[j] ^ ma) & (bv[j] ^ mb);
            }
        }
        __syncthreads();
#pragma unroll
        for (int it = 0; it < NIT; ++it) dreg[it] = dn[it];
        cur = dst;
    }
    // result in bufA, bufB free -> gsum scratch
    u32* res = bufA;
    u32* scratch = bufB;

    // ---- GroupSum: CSA vertical popcount over each class's 1600 gates ----
    // Phase A: 1000 threads: (class c, slot j) CSA 16 gates -> 5 planes (<=16)
    if (t < NC * 100) {
        int c = t / 100, j = t % 100;
        u32 p[12];
#pragma unroll
        for (int q = 0; q < 12; ++q) p[q] = 0;
#pragma unroll
        for (int k = 0; k < 16; ++k) {
            u32 carry = res[c * GPC + k * 100 + j];
#pragma unroll
            for (int q = 0; q < 5; ++q) { u32 s = p[q]; p[q] = s ^ carry; carry = s & carry; }
        }
        u32* sp = scratch + (c * 100 + j) * SSTR;
#pragma unroll
        for (int q = 0; q < 12; ++q) sp[q] = p[q];
    }

    // Phase B: pairwise tree-merge (12-plane ripple adder), 100->50->25->13->7->4->2->1
    const int widths[8] = {100, 50, 25, 13, 7, 4, 2, 1};
    for (int s = 0; s < 7; ++s) {
        int W = widths[s], Wo = widths[s + 1];
        u32 p[12];
        bool act = (t < NC * Wo);
        int c = 0, j = 0;
        __syncthreads();
        if (act) {
            c = t / Wo; j = t % Wo;
            const u32* pa = scratch + (c * 100 + 2 * j) * SSTR;
#pragma unroll
            for (int q = 0; q < 12; ++q) p[q] = pa[q];
            if (2 * j + 1 < W) {
                const u32* pb = scratch + (c * 100 + 2 * j + 1) * SSTR;
                u32 carry = 0;
#pragma unroll
                for (int q = 0; q < 12; ++q) {
                    u32 a = p[q], b = pb[q];
                    u32 xr = a ^ b;
                    p[q] = xr ^ carry;
                    carry = (a & b) | (carry & xr);
                }
            }
        }
        __syncthreads();
        if (act) {
            u32* po = scratch + (c * 100 + j) * SSTR;
#pragma unroll
            for (int q = 0; q < 12; ++q) po[q] = p[q];
        }
    }
    __syncthreads();

    // Phase C: extract per-bit counts, write logits
    if (t < NC * 32) {
        int c = t / 32, bit = t % 32;
        const u32* sp = scratch + (c * 100) * SSTR;
        int cnt = 0;
#pragma unroll
        for (int q = 0; q < 12; ++q) cnt += (int)((sp[q] >> bit) & 1u) << q;
        out[((size_t)w * 32 + bit) * NC + c] = cnt;
    }
}

// ---------------------------------------------------------------------------
extern "C" void kernel_launch(void* const* d_in, const int* in_sizes, int n_in,
                              void* d_out, int out_size, void* d_ws, size_t ws_size,
                              hipStream_t stream) {
    const int* x      = (const int*)d_in[0];  // [4096,784] 0/1
    const int* idx_a0 = (const int*)d_in[1];  // [16000]
    const int* idx_b0 = (const int*)d_in[2];  // [16000]
    const int* neg0   = (const int*)d_in[3];  // [16000,2]
    const int* idx_a  = (const int*)d_in[4];  // [4,16000]
    const int* idx_b  = (const int*)d_in[5];  // [4,16000]
    const int* neg    = (const int*)d_in[6];  // [4,16000,2]
    int* out = (int*)d_out;                   // [4096,10]

    u32* desc = (u32*)d_ws;                   // (NH+1)*SW*4 = 327,680 B

    int ndesc = (NH + 1) * SW;
    desc_kernel<<<(ndesc + 255) / 256, 256, 0, stream>>>(
        idx_a0, idx_b0, neg0, idx_a, idx_b, neg, desc);

    net_kernel<<<NBLK, TPB, 0, stream>>>(x, desc, out);
}

// Round 5
// 87.531 us; speedup vs baseline: 1.8479x; 1.0129x over previous
//
#include <hip/hip_runtime.h>

// CompiledLogicNet fully fused: one block per u32 batch-column (32 samples).
// State [16384] u32 (16000 padded) in LDS, double-buffered. Gathers = LDS reads.
// Thread t owns 4 groups of 4 consecutive gates -> ds_write_b128 stores and
// dwordx4 desc loads. Desc prefetched one layer ahead.

#define NIN   784
#define WIDTH 16000
#define SW    16384    // padded width (16 * TPB)
#define NH    4
#define NC    10
#define GPC   1600     // gates per class
#define NBLK  128      // u32 columns: 4096 batch / 32
#define TPB   1024
#define SSTR  13       // gsum scratch stride: 12 planes + 1 pad

typedef unsigned int u32;

// ---------------------------------------------------------------------------
// Pack (idx_a, idx_b, neg) -> desc[l][g] = ia | ib<<14 | na<<28 | nb<<29,
// padded to SW per layer (pad gates: a=b=0, no neg -> harmless).
__global__ void desc_kernel(const int* __restrict__ ia0, const int* __restrict__ ib0,
                            const int* __restrict__ n0,
                            const int* __restrict__ ia, const int* __restrict__ ib,
                            const int* __restrict__ n, u32* __restrict__ desc) {
    int t = blockIdx.x * blockDim.x + threadIdx.x;
    if (t >= (NH + 1) * SW) return;
    int l = t >> 14;          // t / SW
    int g = t & (SW - 1);     // t % SW
    u32 d = 0;
    if (g < WIDTH) {
        int a, b, na, nb;
        if (l == 0) { a = ia0[g]; b = ib0[g]; na = n0[2 * g]; nb = n0[2 * g + 1]; }
        else {
            int o = (l - 1) * WIDTH + g;
            a = ia[o]; b = ib[o]; na = n[2 * o]; nb = n[2 * o + 1];
        }
        d = (u32)a | ((u32)b << 14) | (na ? (1u << 28) : 0u) | (nb ? (1u << 29) : 0u);
    }
    desc[t] = d;
}

// ---------------------------------------------------------------------------
__launch_bounds__(TPB)
__global__ void net_kernel(const int* __restrict__ x, const u32* __restrict__ desc,
                           int* __restrict__ out) {
    __shared__ __align__(16) u32 xw[NIN];
    __shared__ __align__(16) u32 bufA[SW];
    __shared__ __align__(16) u32 bufB[SW];   // doubles as gsum scratch

    int w = blockIdx.x;
    int t = threadIdx.x;

    // prefetch layer-0 descriptors (4 x dwordx4) while we pack
    uint4 dreg[4];
    {
        const uint4* d0 = (const uint4*)desc;
#pragma unroll
        for (int j = 0; j < 4; ++j) dreg[j] = d0[t + j * TPB];
    }

    // ---- pack: xw[i] bit r = x[w*32+r][i] (coalesced along i) ----
    if (t < NIN) {
        const int* base = x + (size_t)(w * 32) * NIN + t;
        u32 acc = 0;
#pragma unroll
        for (int r = 0; r < 32; ++r)
            acc |= (base[(size_t)r * NIN] != 0 ? 1u : 0u) << r;
        xw[t] = acc;
    }
    __syncthreads();

    // ---- 5 layers, ping-pong LDS ----
    u32* cur = xw;
#pragma unroll
    for (int l = 0; l <= NH; ++l) {
        u32* dst = (l & 1) ? bufB : bufA;   // A,B,A,B,A -> result in bufA
        uint4 dn[4];
        if (l < NH) {
            const uint4* dq = (const uint4*)(desc + (size_t)(l + 1) * SW);
#pragma unroll
            for (int j = 0; j < 4; ++j) dn[j] = dq[t + j * TPB];
        }
#pragma unroll
        for (int j = 0; j < 4; ++j) {
            u32 d0 = dreg[j].x, d1 = dreg[j].y, d2 = dreg[j].z, d3 = dreg[j].w;
            u32 a0 = cur[d0 & 0x3FFFu], b0 = cur[(d0 >> 14) & 0x3FFFu];
            u32 a1 = cur[d1 & 0x3FFFu], b1 = cur[(d1 >> 14) & 0x3FFFu];
            u32 a2 = cur[d2 & 0x3FFFu], b2 = cur[(d2 >> 14) & 0x3FFFu];
            u32 a3 = cur[d3 & 0x3FFFu], b3 = cur[(d3 >> 14) & 0x3FFFu];
            uint4 r;
            r.x = (a0 ^ (0u - ((d0 >> 28) & 1u))) & (b0 ^ (0u - ((d0 >> 29) & 1u)));
            r.y = (a1 ^ (0u - ((d1 >> 28) & 1u))) & (b1 ^ (0u - ((d1 >> 29) & 1u)));
            r.z = (a2 ^ (0u - ((d2 >> 28) & 1u))) & (b2 ^ (0u - ((d2 >> 29) & 1u)));
            r.w = (a3 ^ (0u - ((d3 >> 28) & 1u))) & (b3 ^ (0u - ((d3 >> 29) & 1u)));
            *(uint4*)(dst + 4 * (t + j * TPB)) = r;   // ds_write_b128, conflict-free
        }
        __syncthreads();
#pragma unroll
        for (int j = 0; j < 4; ++j) dreg[j] = dn[j];
        cur = dst;
    }
    // result in bufA, bufB free -> gsum scratch
    u32* res = bufA;
    u32* scratch = bufB;

    // ---- GroupSum: CSA vertical popcount over each class's 1600 gates ----
    // Phase A: 1000 threads: (class c, slot j) CSA 16 gates -> 5 planes (<=16)
    if (t < NC * 100) {
        int c = t / 100, j = t % 100;
        u32 p[12];
#pragma unroll
        for (int q = 0; q < 12; ++q) p[q] = 0;
#pragma unroll
        for (int k = 0; k < 16; ++k) {
            u32 carry = res[c * GPC + k * 100 + j];
#pragma unroll
            for (int q = 0; q < 5; ++q) { u32 s = p[q]; p[q] = s ^ carry; carry = s & carry; }
        }
        u32* sp = scratch + (c * 100 + j) * SSTR;
#pragma unroll
        for (int q = 0; q < 12; ++q) sp[q] = p[q];
    }

    // Phase B: 4-way tree-merge (12-plane ripple adder), 100->25->7->2->1
    const int widths[5] = {100, 25, 7, 2, 1};
    for (int s = 0; s < 4; ++s) {
        int W = widths[s], Wo = widths[s + 1];
        u32 p[12];
        bool act = (t < NC * Wo);
        int c = 0, j = 0;
        __syncthreads();
        if (act) {
            c = t / Wo; j = t % Wo;
            const u32* pa = scratch + (c * 100 + 4 * j) * SSTR;
#pragma unroll
            for (int q = 0; q < 12; ++q) p[q] = pa[q];
#pragma unroll
            for (int k = 1; k < 4; ++k) {
                if (4 * j + k < W) {
                    const u32* pb = scratch + (c * 100 + 4 * j + k) * SSTR;
                    u32 carry = 0;
#pragma unroll
                    for (int q = 0; q < 12; ++q) {
                        u32 a = p[q], b = pb[q];
                        u32 xr = a ^ b;
                        p[q] = xr ^ carry;
                        carry = (a & b) | (carry & xr);
                    }
                }
            }
        }
        __syncthreads();
        if (act) {
            u32* po = scratch + (c * 100 + j) * SSTR;
#pragma unroll
            for (int q = 0; q < 12; ++q) po[q] = p[q];
        }
    }
    __syncthreads();

    // Phase C: extract per-bit counts, write logits
    if (t < NC * 32) {
        int c = t / 32, bit = t % 32;
        const u32* sp = scratch + (c * 100) * SSTR;
        int cnt = 0;
#pragma unroll
        for (int q = 0; q < 12; ++q) cnt += (int)((sp[q] >> bit) & 1u) << q;
        out[((size_t)w * 32 + bit) * NC + c] = cnt;
    }
}

// ---------------------------------------------------------------------------
extern "C" void kernel_launch(void* const* d_in, const int* in_sizes, int n_in,
                              void* d_out, int out_size, void* d_ws, size_t ws_size,
                              hipStream_t stream) {
    const int* x      = (const int*)d_in[0];  // [4096,784] 0/1
    const int* idx_a0 = (const int*)d_in[1];  // [16000]
    const int* idx_b0 = (const int*)d_in[2];  // [16000]
    const int* neg0   = (const int*)d_in[3];  // [16000,2]
    const int* idx_a  = (const int*)d_in[4];  // [4,16000]
    const int* idx_b  = (const int*)d_in[5];  // [4,16000]
    const int* neg    = (const int*)d_in[6];  // [4,16000,2]
    int* out = (int*)d_out;                   // [4096,10]

    u32* desc = (u32*)d_ws;                   // (NH+1)*SW*4 = 327,680 B

    int ndesc = (NH + 1) * SW;
    desc_kernel<<<(ndesc + 255) / 256, 256, 0, stream>>>(
        idx_a0, idx_b0, neg0, idx_a, idx_b, neg, desc);

    net_kernel<<<NBLK, TPB, 0, stream>>>(x, desc, out);
}